// Round 1
// baseline (483.514 us; speedup 1.0000x reference)
//
#include <hip/hip_runtime.h>
#include <math.h>

// Scatter-max of E edge weights into a zeroed [N,N] fp32 matrix.
// Weights are uniform[0,1) => non-negative, so int-compare == float-compare
// on the raw bits. atomicMax on int* aliasing the float output is exact.
__global__ void scatter_max_vec4(const float4* __restrict__ w4,
                                 const int4* __restrict__ r4,
                                 const int4* __restrict__ c4,
                                 int* __restrict__ out_bits,
                                 int num_vec, int n) {
    int i = blockIdx.x * blockDim.x + threadIdx.x;
    int stride = gridDim.x * blockDim.x;
    for (; i < num_vec; i += stride) {
        float4 w = w4[i];
        int4 r = r4[i];
        int4 c = c4[i];
        atomicMax(&out_bits[(long long)r.x * n + c.x], __float_as_int(w.x));
        atomicMax(&out_bits[(long long)r.y * n + c.y], __float_as_int(w.y));
        atomicMax(&out_bits[(long long)r.z * n + c.z], __float_as_int(w.z));
        atomicMax(&out_bits[(long long)r.w * n + c.w], __float_as_int(w.w));
    }
}

// Tail handler in case E % 4 != 0 (not expected here, but cheap insurance).
__global__ void scatter_max_tail(const float* __restrict__ w,
                                 const int* __restrict__ rows,
                                 const int* __restrict__ cols,
                                 int* __restrict__ out_bits,
                                 int start, int E, int n) {
    int i = start + blockIdx.x * blockDim.x + threadIdx.x;
    if (i < E) {
        atomicMax(&out_bits[(long long)rows[i] * n + cols[i]],
                  __float_as_int(w[i]));
    }
}

extern "C" void kernel_launch(void* const* d_in, const int* in_sizes, int n_in,
                              void* d_out, int out_size, void* d_ws, size_t ws_size,
                              hipStream_t stream) {
    const float* weights = (const float*)d_in[0];
    const int* rows = (const int*)d_in[1];
    const int* cols = (const int*)d_in[2];
    const int E = in_sizes[0];

    // N from output size (out is N*N). E.g. 67108864 -> 8192.
    int n = (int)(sqrt((double)out_size) + 0.5);

    int* out_bits = (int*)d_out;

    // Zero the output (poisoned with 0xAA before every timed call).
    hipMemsetAsync(d_out, 0, (size_t)out_size * sizeof(float), stream);

    int num_vec = E / 4;
    int tail_start = num_vec * 4;

    if (num_vec > 0) {
        const int block = 256;
        int grid = (num_vec + block - 1) / block;
        // Cap grid; grid-stride loop covers the rest. 256 CUs * 8 blocks.
        if (grid > 2048) grid = 2048;
        scatter_max_vec4<<<grid, block, 0, stream>>>(
            (const float4*)weights, (const int4*)rows, (const int4*)cols,
            out_bits, num_vec, n);
    }
    if (tail_start < E) {
        const int block = 256;
        int grid = (E - tail_start + block - 1) / block;
        scatter_max_tail<<<grid, block, 0, stream>>>(
            weights, rows, cols, out_bits, tail_start, E, n);
    }
}